// Round 5
// baseline (521.635 us; speedup 1.0000x reference)
//
#include <hip/hip_runtime.h>
#include <hip/hip_bf16.h>

// Shapes (fixed): B=32, S=2048, E=1024, U=1024. M = B*S = 65536.
// score[m] = v . tanh( lhs[m,:] @ (W+U)^T )  -- bf16 MFMA GEMM on COMPACTED valid rows
// out[b,:] = sum_s softmax_s(masked score)[s] * lhs[b,s,:]
//
// ws: wsum bf16 [0,2MB) | score [2MB,+256KB) | alpha [+256KB) | ridx u16 [2.5MB,+128KB)
//     | cnt i32 [2.625MB,+128B) | Ab bf16 [2.75MB,+128MB) | part f32 [+8MB)

typedef short bf16x8 __attribute__((ext_vector_type(8)));
typedef float f32x4  __attribute__((ext_vector_type(4)));
typedef unsigned short u16x8 __attribute__((ext_vector_type(8)));

static __device__ __forceinline__ unsigned short f2bf(float f) {
    unsigned int x = __float_as_uint(f);
    unsigned int r = x + 0x7FFFu + ((x >> 16) & 1u);   // RNE
    return (unsigned short)(r >> 16);
}

static __device__ __forceinline__ float fast_tanh(float x) {
    float e = __builtin_amdgcn_exp2f(x * 2.885390082f);   // e^{2x}
    float r = __builtin_amdgcn_rcpf(e + 1.0f);
    return __builtin_fmaf(-2.0f, r, 1.0f);
}

// ---------------- K0: Wsum = bf16(W+U), zero score/alpha/out ----------------
__global__ __launch_bounds__(256)
void prep_kernel(const float* __restrict__ W, const float* __restrict__ U,
                 unsigned short* __restrict__ wsum,
                 float* __restrict__ score, float* __restrict__ alpha,
                 float* __restrict__ out) {
    int g = blockIdx.x * 256 + threadIdx.x;
    int i4 = g * 4;
    float4 w = *(const float4*)&W[i4];
    float4 u = *(const float4*)&U[i4];
    ushort4 h;
    h.x = f2bf(w.x + u.x); h.y = f2bf(w.y + u.y);
    h.z = f2bf(w.z + u.z); h.w = f2bf(w.w + u.w);
    *(ushort4*)&wsum[i4] = h;
    if (g < 65536) { score[g] = 0.0f; alpha[g] = 0.0f; }
    if (g < 32768) out[g] = 0.0f;
}

// ---------------- K1: per-batch valid-row index (block scan) ----------------
__global__ __launch_bounds__(256)
void index_kernel(const int* __restrict__ mask, unsigned short* __restrict__ ridx,
                  int* __restrict__ cnt) {
    int b = blockIdx.x, t = threadIdx.x;
    const int* mrow = mask + b * 2048;
    int m[8], c = 0;
#pragma unroll
    for (int j = 0; j < 8; ++j) { m[j] = mrow[t * 8 + j]; c += (m[j] != 0); }
    __shared__ int sc[256];
    sc[t] = c;
    __syncthreads();
    for (int off = 1; off < 256; off <<= 1) {
        int v = (t >= off) ? sc[t - off] : 0;
        __syncthreads();
        sc[t] += v;
        __syncthreads();
    }
    int base = sc[t] - c;
    unsigned short* rb = ridx + b * 2048;
#pragma unroll
    for (int j = 0; j < 8; ++j)
        if (m[j]) rb[base++] = (unsigned short)(t * 8 + j);
    if (t == 255) cnt[b] = sc[255];
}

// ---------------- K2: gather valid rows -> bf16 compact (zero-pad to x128) ----------------
__global__ __launch_bounds__(256)
void gather_convert(const float* __restrict__ lhs, const unsigned short* __restrict__ ridx,
                    const int* __restrict__ cnt, unsigned short* __restrict__ Ab) {
    int b = blockIdx.y;
    int c = cnt[b];
    int cpad = (c + 127) & ~127;
    int r = blockIdx.x * 4 + (threadIdx.x >> 6);
    int lt = threadIdx.x & 63;
    if (r >= cpad) return;
    unsigned short* dst = Ab + ((size_t)b * 2048 + r) * 1024 + lt * 16;
    if (r < c) {
        int s = ridx[b * 2048 + r];
        const float* src = lhs + ((size_t)b * 2048 + s) * 1024 + lt * 16;
        float4 a0 = *(const float4*)(src + 0);
        float4 a1 = *(const float4*)(src + 4);
        float4 a2 = *(const float4*)(src + 8);
        float4 a3 = *(const float4*)(src + 12);
        u16x8 h0, h1;
        h0[0] = f2bf(a0.x); h0[1] = f2bf(a0.y); h0[2] = f2bf(a0.z); h0[3] = f2bf(a0.w);
        h0[4] = f2bf(a1.x); h0[5] = f2bf(a1.y); h0[6] = f2bf(a1.z); h0[7] = f2bf(a1.w);
        h1[0] = f2bf(a2.x); h1[1] = f2bf(a2.y); h1[2] = f2bf(a2.z); h1[3] = f2bf(a2.w);
        h1[4] = f2bf(a3.x); h1[5] = f2bf(a3.y); h1[6] = f2bf(a3.z); h1[7] = f2bf(a3.w);
        *(u16x8*)(dst + 0) = h0;
        *(u16x8*)(dst + 8) = h1;
    } else {
        u16x8 z = (u16x8){0,0,0,0,0,0,0,0};
        *(u16x8*)(dst + 0) = z;
        *(u16x8*)(dst + 8) = z;
    }
}

// ---------------- K3: fused score GEMM, BK=64, XOR-swizzled LDS, XCD-swizzled grid ----
// LDS tile: 128 rows x 64 k bf16 = 16 KB = 1024 x 16B chunks.
// Chunk (row r, kchunk kc) lives at LDS slot r*8 + (kc ^ (r&7))  [bank-conflict-free reads].
// Staging permutes the GLOBAL address per lane (LDS side stays wave-uniform + lane*16).
__global__ __launch_bounds__(256)
void score_gemm_bf16(const unsigned short* __restrict__ Ab,
                     const unsigned short* __restrict__ Bw,
                     const float* __restrict__ v, const int* __restrict__ cnt,
                     float* __restrict__ score) {
    const int K = 1024;
    __shared__ __align__(16) unsigned short As[128 * 64];
    __shared__ __align__(16) unsigned short Bs[128 * 64];

    // XCD swizzle: 64-block groups; within a group, bid%8 (=XCD) picks the m-tile,
    // (bid>>3)&7 picks n. => one XCD sees one m-tile's A-slab across all 8 n-tiles.
    const int bid    = (int)blockIdx.x;          // 0..4095
    const int group  = bid >> 6;
    const int mt     = (group << 3) + (bid & 7); // 0..511
    const int nI     = (bid >> 3) & 7;
    const int b      = mt >> 4;
    const int lm0    = (mt & 15) << 7;
    const int c      = cnt[b];
    if (lm0 >= ((c + 127) & ~127)) return;
    const int m0     = (b << 11) + lm0;
    const int n0     = nI << 7;

    const int t    = threadIdx.x;
    const int lane = t & 63;
    const int wave = t >> 6;
    const int wm   = (wave & 1) * 64;
    const int wn   = (wave >> 1) * 64;
    const int ml   = lane & 15;
    const int q    = lane >> 4;
    const int xorv = ml & 7;

    f32x4 acc[4][4];
#pragma unroll
    for (int i = 0; i < 4; ++i)
#pragma unroll
        for (int j = 0; j < 4; ++j)
            acc[i][j] = (f32x4){0.f, 0.f, 0.f, 0.f};

    const unsigned short* gA[4];
    const unsigned short* gB[4];
    unsigned short* lA[4];
    unsigned short* lB[4];
#pragma unroll
    for (int p = 0; p < 4; ++p) {
        int l   = p * 256 + wave * 64 + lane;   // LDS slot this lane fills
        int row = l >> 3;
        int kc  = (l & 7) ^ (row & 7);          // global chunk that belongs in slot l
        gA[p] = Ab + (size_t)(m0 + row) * K + kc * 8;
        gB[p] = Bw + (size_t)(n0 + row) * K + kc * 8;
        lA[p] = &As[(p * 4 + wave) * 512];      // wave-uniform base; HW adds lane*16B
        lB[p] = &Bs[(p * 4 + wave) * 512];
    }

    for (int kk = 0; kk < K; kk += 64) {
#pragma unroll
        for (int p = 0; p < 4; ++p) {
            __builtin_amdgcn_global_load_lds((const __attribute__((address_space(1))) unsigned int*)gA[p],
                                             (__attribute__((address_space(3))) unsigned int*)lA[p], 16, 0, 0);
            __builtin_amdgcn_global_load_lds((const __attribute__((address_space(1))) unsigned int*)gB[p],
                                             (__attribute__((address_space(3))) unsigned int*)lB[p], 16, 0, 0);
            gA[p] += 64; gB[p] += 64;
        }
        __syncthreads();

#pragma unroll
        for (int s = 0; s < 2; ++s) {
            const int koff = ((s * 4 + q) ^ xorv) * 8;   // swizzled k-chunk offset (shorts)
            bf16x8 af[4], bf[4];
#pragma unroll
            for (int i = 0; i < 4; ++i)
                af[i] = *(const bf16x8*)&As[(wm + i * 16 + ml) * 64 + koff];
#pragma unroll
            for (int j = 0; j < 4; ++j)
                bf[j] = *(const bf16x8*)&Bs[(wn + j * 16 + ml) * 64 + koff];
#pragma unroll
            for (int i = 0; i < 4; ++i)
#pragma unroll
                for (int j = 0; j < 4; ++j)
                    acc[i][j] = __builtin_amdgcn_mfma_f32_16x16x32_bf16(af[i], bf[j], acc[i][j], 0, 0, 0);
        }
        __syncthreads();
    }

    // score[m] += sum_n v[n]*tanh(P[m,n]).  D layout: col=lane&15, row=q*4+reg.
    float vw[4];
#pragma unroll
    for (int j = 0; j < 4; ++j)
        vw[j] = v[n0 + wn + j * 16 + ml];

#pragma unroll
    for (int i = 0; i < 4; ++i) {
#pragma unroll
        for (int r = 0; r < 4; ++r) {
            float val = 0.f;
#pragma unroll
            for (int j = 0; j < 4; ++j)
                val += fast_tanh(acc[i][j][r]) * vw[j];
#pragma unroll
            for (int off = 8; off > 0; off >>= 1)
                val += __shfl_xor(val, off, 64);
            if (ml == 0)
                atomicAdd(&score[m0 + wm + i * 16 + q * 4 + r], val);
        }
    }
}

// ---------------- K3-fallback: fp32-staged GEMM over ALL rows (small ws) ----------------
#define LDSS 40
__global__ __launch_bounds__(256)
void score_gemm_f32stage(const float* __restrict__ A, const unsigned short* __restrict__ Bw,
                         const float* __restrict__ v, float* __restrict__ score) {
    const int K = 1024;
    __shared__ __align__(16) unsigned short As[128][LDSS];
    __shared__ __align__(16) unsigned short Bs[128][LDSS];
    const int n0 = (int)blockIdx.x * 128;
    const int m0 = (int)blockIdx.y * 128;
    const int t = threadIdx.x, lane = t & 63, wave = t >> 6;
    const int wm = (wave & 1) * 64, wn = (wave >> 1) * 64;
    const int ml = lane & 15, q = lane >> 4;
    f32x4 acc[4][4];
#pragma unroll
    for (int i = 0; i < 4; ++i)
#pragma unroll
        for (int j = 0; j < 4; ++j) acc[i][j] = (f32x4){0.f,0.f,0.f,0.f};
    const int sr = t >> 3, sc = (t & 7) * 4;
    for (int kk = 0; kk < K; kk += 32) {
#pragma unroll
        for (int p = 0; p < 4; ++p) {
            int r = sr + p * 32;
            float4 va = *(const float4*)&A[(size_t)(m0 + r) * K + kk + sc];
            ushort4 h; h.x = f2bf(va.x); h.y = f2bf(va.y); h.z = f2bf(va.z); h.w = f2bf(va.w);
            *(ushort4*)&As[r][sc] = h;
            ushort4 vb = *(const ushort4*)&Bw[(size_t)(n0 + r) * K + kk + sc];
            *(ushort4*)&Bs[r][sc] = vb;
        }
        __syncthreads();
        bf16x8 af[4], bf[4];
#pragma unroll
        for (int i = 0; i < 4; ++i) af[i] = *(const bf16x8*)&As[wm + i * 16 + ml][q * 8];
#pragma unroll
        for (int j = 0; j < 4; ++j) bf[j] = *(const bf16x8*)&Bs[wn + j * 16 + ml][q * 8];
#pragma unroll
        for (int i = 0; i < 4; ++i)
#pragma unroll
            for (int j = 0; j < 4; ++j)
                acc[i][j] = __builtin_amdgcn_mfma_f32_16x16x32_bf16(af[i], bf[j], acc[i][j], 0, 0, 0);
        __syncthreads();
    }
    float vw[4];
#pragma unroll
    for (int j = 0; j < 4; ++j) vw[j] = v[n0 + wn + j * 16 + ml];
#pragma unroll
    for (int i = 0; i < 4; ++i)
#pragma unroll
        for (int r = 0; r < 4; ++r) {
            float val = 0.f;
#pragma unroll
            for (int j = 0; j < 4; ++j) val += fast_tanh(acc[i][j][r]) * vw[j];
#pragma unroll
            for (int off = 8; off > 0; off >>= 1) val += __shfl_xor(val, off, 64);
            if (ml == 0) atomicAdd(&score[m0 + wm + i * 16 + q * 4 + r], val);
        }
}

// ---------------- K4: softmax over compact scores, scatter alpha ----------------
__global__ __launch_bounds__(256)
void softmax_compact(const float* __restrict__ score, const unsigned short* __restrict__ ridx,
                     const int* __restrict__ cnt, float* __restrict__ alpha) {
    int b = blockIdx.x, t = threadIdx.x;
    int c = cnt[b];
    __shared__ float red[8];
    float sc[8];
    float mx = -1e30f;
#pragma unroll
    for (int i = 0; i < 8; ++i) {
        int k = i * 256 + t;
        sc[i] = (k < c) ? score[b * 2048 + k] : -1e30f;
        mx = fmaxf(mx, sc[i]);
    }
#pragma unroll
    for (int off = 32; off > 0; off >>= 1)
        mx = fmaxf(mx, __shfl_xor(mx, off, 64));
    if ((t & 63) == 0) red[t >> 6] = mx;
    __syncthreads();
    mx = fmaxf(fmaxf(red[0], red[1]), fmaxf(red[2], red[3]));
    float e[8], sum = 0.f;
#pragma unroll
    for (int i = 0; i < 8; ++i) {
        int k = i * 256 + t;
        e[i] = (k < c) ? __expf(sc[i] - mx) : 0.f;
        sum += e[i];
    }
#pragma unroll
    for (int off = 32; off > 0; off >>= 1)
        sum += __shfl_xor(sum, off, 64);
    if ((t & 63) == 0) red[4 + (t >> 6)] = sum;
    __syncthreads();
    float inv = 1.0f / (red[4] + red[5] + red[6] + red[7]);
#pragma unroll
    for (int i = 0; i < 8; ++i) {
        int k = i * 256 + t;
        if (k < c) {
            int s = ridx[b * 2048 + k];
            alpha[b * 2048 + s] = e[i] * inv;
        }
    }
}

// ---------------- K4-fallback: masked softmax (full rows) ----------------
__global__ __launch_bounds__(256)
void softmax_kernel(const float* __restrict__ score, const int* __restrict__ mask,
                    float* __restrict__ alpha) {
    const int S = 2048;
    int b = blockIdx.x, t = threadIdx.x;
    __shared__ float red[8];
    float sc[8]; int vd[8];
    float mx = -1e30f;
#pragma unroll
    for (int i = 0; i < 8; ++i) {
        int s = i * 256 + t;
        vd[i] = mask[b * S + s];
        sc[i] = score[b * S + s];
        if (vd[i]) mx = fmaxf(mx, sc[i]);
    }
#pragma unroll
    for (int off = 32; off > 0; off >>= 1)
        mx = fmaxf(mx, __shfl_xor(mx, off, 64));
    if ((t & 63) == 0) red[t >> 6] = mx;
    __syncthreads();
    mx = fmaxf(fmaxf(red[0], red[1]), fmaxf(red[2], red[3]));
    float e[8]; float sum = 0.f;
#pragma unroll
    for (int i = 0; i < 8; ++i) {
        e[i] = vd[i] ? __expf(sc[i] - mx) : 0.f;
        sum += e[i];
    }
#pragma unroll
    for (int off = 32; off > 0; off >>= 1)
        sum += __shfl_xor(sum, off, 64);
    if ((t & 63) == 0) red[4 + (t >> 6)] = sum;
    __syncthreads();
    float inv = 1.0f / (red[4] + red[5] + red[6] + red[7]);
#pragma unroll
    for (int i = 0; i < 8; ++i)
        alpha[b * S + i * 256 + t] = e[i] * inv;
}

// ---------------- K5a: per-(b,seg) partial weighted sums (no atomics) ----------------
__global__ __launch_bounds__(256)
void wsum_partial(const float* __restrict__ lhs, const float* __restrict__ alpha,
                  float* __restrict__ part) {
    const int S = 2048, E = 1024;
    int b = blockIdx.x >> 6;
    int seg = blockIdx.x & 63;
    int t = threadIdx.x;
    int s0 = seg * 32;
    const float* base = lhs + ((size_t)b * S + s0) * E + t * 4;
    const float* ap = alpha + b * S + s0;
    float4 acc = {0.f, 0.f, 0.f, 0.f};
#pragma unroll 4
    for (int s = 0; s < 32; ++s) {
        float a = ap[s];
        if (a != 0.f) {
            float4 x = *(const float4*)(base + (size_t)s * E);
            acc.x += a * x.x; acc.y += a * x.y; acc.z += a * x.z; acc.w += a * x.w;
        }
    }
    *(float4*)(part + (size_t)blockIdx.x * E + t * 4) = acc;
}

// ---------------- K5b: reduce partials -> out ----------------
__global__ __launch_bounds__(256)
void wsum_reduce(const float* __restrict__ part, float* __restrict__ out) {
    int b = blockIdx.x >> 2;
    int e = (blockIdx.x & 3) * 256 + threadIdx.x;
    const float* p = part + (size_t)b * 64 * 1024 + e;
    float sum = 0.f;
#pragma unroll
    for (int s = 0; s < 64; ++s)
        sum += p[(size_t)s * 1024];
    out[b * 1024 + e] = sum;
}

// ---------------- K5-fallback: atomic weighted sum ----------------
__global__ __launch_bounds__(256)
void wsum_kernel(const float* __restrict__ lhs, const float* __restrict__ alpha,
                 float* __restrict__ out) {
    const int S = 2048, E = 1024;
    int b = blockIdx.x >> 6;
    int seg = blockIdx.x & 63;
    int t = threadIdx.x;
    int s0 = seg * 32;
    const float* base = lhs + ((size_t)b * S + s0) * E + t * 4;
    const float* ap = alpha + b * S + s0;
    float4 acc = {0.f, 0.f, 0.f, 0.f};
#pragma unroll 4
    for (int s = 0; s < 32; ++s) {
        float a = ap[s];
        if (a != 0.f) {
            float4 x = *(const float4*)(base + (size_t)s * E);
            acc.x += a * x.x; acc.y += a * x.y; acc.z += a * x.z; acc.w += a * x.w;
        }
    }
    float* o = out + b * E + t * 4;
    atomicAdd(o + 0, acc.x);
    atomicAdd(o + 1, acc.y);
    atomicAdd(o + 2, acc.z);
    atomicAdd(o + 3, acc.w);
}

extern "C" void kernel_launch(void* const* d_in, const int* in_sizes, int n_in,
                              void* d_out, int out_size, void* d_ws, size_t ws_size,
                              hipStream_t stream) {
    const float* lhs  = (const float*)d_in[0];
    const int*   mask = (const int*)d_in[1];
    const float* W    = (const float*)d_in[2];
    const float* Um   = (const float*)d_in[3];
    const float* v    = (const float*)d_in[4];
    float* out = (float*)d_out;

    char* ws = (char*)d_ws;
    unsigned short* wsum  = (unsigned short*)ws;                      // 2 MB
    float* score          = (float*)(ws + 2048u * 1024u);             // 256 KB
    float* alpha          = (float*)(ws + 2304u * 1024u);             // 256 KB
    unsigned short* ridx  = (unsigned short*)(ws + 2560u * 1024u);    // 128 KB
    int* cnt              = (int*)(ws + 2688u * 1024u);               // 128 B
    unsigned short* Ab    = (unsigned short*)(ws + 2816u * 1024u);    // 128 MB
    float* part           = (float*)(ws + 2816u * 1024u + 131072u * 1024u); // 8 MB
    const size_t need = 2816ull * 1024ull + 131072ull * 1024ull + 8192ull * 1024ull;

    prep_kernel<<<1024, 256, 0, stream>>>(W, Um, wsum, score, alpha, out);
    if (ws_size >= need) {
        index_kernel<<<32, 256, 0, stream>>>(mask, ridx, cnt);
        dim3 gg(512, 32);
        gather_convert<<<gg, 256, 0, stream>>>(lhs, ridx, cnt, Ab);
        score_gemm_bf16<<<4096, 256, 0, stream>>>(Ab, wsum, v, cnt, score);
        softmax_compact<<<32, 256, 0, stream>>>(score, ridx, cnt, alpha);
        wsum_partial<<<2048, 256, 0, stream>>>(lhs, alpha, part);
        wsum_reduce<<<128, 256, 0, stream>>>(part, out);
    } else {
        dim3 g1(8, 512);
        score_gemm_f32stage<<<g1, 256, 0, stream>>>(lhs, wsum, v, score);
        softmax_kernel<<<32, 256, 0, stream>>>(score, mask, alpha);
        wsum_kernel<<<2048, 256, 0, stream>>>(lhs, alpha, out);
    }
}

// Round 6
// 514.143 us; speedup vs baseline: 1.0146x; 1.0146x over previous
//
#include <hip/hip_runtime.h>
#include <hip/hip_bf16.h>

// Shapes (fixed): B=32, S=2048, E=1024, U=1024. M = B*S = 65536.
// score[m] = v . tanh( lhs[m,:] @ (W+U)^T )  -- bf16 MFMA GEMM on COMPACTED valid rows
// out[b,:] = sum_s softmax(score)[s] * row[s]  -- consumed in COMPACT order (sum is order-free)
//
// ws: wsum bf16 [0,2MB) | score [2MB,+256KB) | alphac [+256KB) | ridx u16 [2.5MB,+128KB)
//     | cnt i32 [2.625MB,+128B) | Ab bf16 [2.75MB,+128MB)

typedef short bf16x8 __attribute__((ext_vector_type(8)));
typedef float f32x4  __attribute__((ext_vector_type(4)));
typedef unsigned short u16x8 __attribute__((ext_vector_type(8)));

static __device__ __forceinline__ unsigned short f2bf(float f) {
    unsigned int x = __float_as_uint(f);
    unsigned int r = x + 0x7FFFu + ((x >> 16) & 1u);   // RNE
    return (unsigned short)(r >> 16);
}

static __device__ __forceinline__ float fast_tanh(float x) {
    float e = __builtin_amdgcn_exp2f(x * 2.885390082f);   // e^{2x}
    float r = __builtin_amdgcn_rcpf(e + 1.0f);
    return __builtin_fmaf(-2.0f, r, 1.0f);
}

// ---------------- K0: [blocks 0..1023] Wsum=bf16(W+U), zero score/out
//                      [blocks 1024..1055] per-batch valid-row index scan ----------------
__global__ __launch_bounds__(256)
void prep_index(const float* __restrict__ W, const float* __restrict__ U,
                const int* __restrict__ mask,
                unsigned short* __restrict__ wsum,
                float* __restrict__ score, float* __restrict__ out,
                unsigned short* __restrict__ ridx, int* __restrict__ cnt) {
    __shared__ int sc[256];
    int blk = blockIdx.x, t = threadIdx.x;
    if (blk < 1024) {
        int g = blk * 256 + t;
        int i4 = g * 4;
        float4 w = *(const float4*)&W[i4];
        float4 u = *(const float4*)&U[i4];
        ushort4 h;
        h.x = f2bf(w.x + u.x); h.y = f2bf(w.y + u.y);
        h.z = f2bf(w.z + u.z); h.w = f2bf(w.w + u.w);
        *(ushort4*)&wsum[i4] = h;
        if (g < 65536) score[g] = 0.0f;
        if (g < 32768) out[g] = 0.0f;
    } else {
        int b = blk - 1024;
        const int* mrow = mask + b * 2048;
        int m[8], c = 0;
#pragma unroll
        for (int j = 0; j < 8; ++j) { m[j] = mrow[t * 8 + j]; c += (m[j] != 0); }
        sc[t] = c;
        __syncthreads();
        for (int off = 1; off < 256; off <<= 1) {
            int v = (t >= off) ? sc[t - off] : 0;
            __syncthreads();
            sc[t] += v;
            __syncthreads();
        }
        int base = sc[t] - c;
        unsigned short* rb = ridx + b * 2048;
#pragma unroll
        for (int j = 0; j < 8; ++j)
            if (m[j]) rb[base++] = (unsigned short)(t * 8 + j);
        if (t == 255) cnt[b] = sc[255];
    }
}

// ---------------- K1: gather valid rows -> bf16 compact (zero-pad to x128) ----------------
__global__ __launch_bounds__(256)
void gather_convert(const float* __restrict__ lhs, const unsigned short* __restrict__ ridx,
                    const int* __restrict__ cnt, unsigned short* __restrict__ Ab) {
    int b = blockIdx.y;
    int c = cnt[b];
    int cpad = (c + 127) & ~127;
    int r = blockIdx.x * 4 + (threadIdx.x >> 6);
    int lt = threadIdx.x & 63;
    if (r >= cpad) return;
    unsigned short* dst = Ab + ((size_t)b * 2048 + r) * 1024 + lt * 16;
    if (r < c) {
        int s = ridx[b * 2048 + r];
        const float* src = lhs + ((size_t)b * 2048 + s) * 1024 + lt * 16;
        float4 a0 = *(const float4*)(src + 0);
        float4 a1 = *(const float4*)(src + 4);
        float4 a2 = *(const float4*)(src + 8);
        float4 a3 = *(const float4*)(src + 12);
        u16x8 h0, h1;
        h0[0] = f2bf(a0.x); h0[1] = f2bf(a0.y); h0[2] = f2bf(a0.z); h0[3] = f2bf(a0.w);
        h0[4] = f2bf(a1.x); h0[5] = f2bf(a1.y); h0[6] = f2bf(a1.z); h0[7] = f2bf(a1.w);
        h1[0] = f2bf(a2.x); h1[1] = f2bf(a2.y); h1[2] = f2bf(a2.z); h1[3] = f2bf(a2.w);
        h1[4] = f2bf(a3.x); h1[5] = f2bf(a3.y); h1[6] = f2bf(a3.z); h1[7] = f2bf(a3.w);
        *(u16x8*)(dst + 0) = h0;
        *(u16x8*)(dst + 8) = h1;
    } else {
        u16x8 z = (u16x8){0,0,0,0,0,0,0,0};
        *(u16x8*)(dst + 0) = z;
        *(u16x8*)(dst + 8) = z;
    }
}

// ---------------- K2: fused score GEMM, BK=64, XOR-swizzled LDS, XCD-swizzled grid ----
__global__ __launch_bounds__(256)
void score_gemm_bf16(const unsigned short* __restrict__ Ab,
                     const unsigned short* __restrict__ Bw,
                     const float* __restrict__ v, const int* __restrict__ cnt,
                     float* __restrict__ score) {
    const int K = 1024;
    __shared__ __align__(16) unsigned short As[128 * 64];
    __shared__ __align__(16) unsigned short Bs[128 * 64];

    const int bid    = (int)blockIdx.x;          // 0..4095
    const int group  = bid >> 6;
    const int mt     = (group << 3) + (bid & 7); // 0..511
    const int nI     = (bid >> 3) & 7;
    const int b      = mt >> 4;
    const int lm0    = (mt & 15) << 7;
    const int c      = cnt[b];
    if (lm0 >= ((c + 127) & ~127)) return;
    const int m0     = (b << 11) + lm0;
    const int n0     = nI << 7;

    const int t    = threadIdx.x;
    const int lane = t & 63;
    const int wave = t >> 6;
    const int wm   = (wave & 1) * 64;
    const int wn   = (wave >> 1) * 64;
    const int ml   = lane & 15;
    const int q    = lane >> 4;
    const int xorv = ml & 7;

    f32x4 acc[4][4];
#pragma unroll
    for (int i = 0; i < 4; ++i)
#pragma unroll
        for (int j = 0; j < 4; ++j)
            acc[i][j] = (f32x4){0.f, 0.f, 0.f, 0.f};

    const unsigned short* gA[4];
    const unsigned short* gB[4];
    unsigned short* lA[4];
    unsigned short* lB[4];
#pragma unroll
    for (int p = 0; p < 4; ++p) {
        int l   = p * 256 + wave * 64 + lane;
        int row = l >> 3;
        int kc  = (l & 7) ^ (row & 7);
        gA[p] = Ab + (size_t)(m0 + row) * K + kc * 8;
        gB[p] = Bw + (size_t)(n0 + row) * K + kc * 8;
        lA[p] = &As[(p * 4 + wave) * 512];
        lB[p] = &Bs[(p * 4 + wave) * 512];
    }

    for (int kk = 0; kk < K; kk += 64) {
#pragma unroll
        for (int p = 0; p < 4; ++p) {
            __builtin_amdgcn_global_load_lds((const __attribute__((address_space(1))) unsigned int*)gA[p],
                                             (__attribute__((address_space(3))) unsigned int*)lA[p], 16, 0, 0);
            __builtin_amdgcn_global_load_lds((const __attribute__((address_space(1))) unsigned int*)gB[p],
                                             (__attribute__((address_space(3))) unsigned int*)lB[p], 16, 0, 0);
            gA[p] += 64; gB[p] += 64;
        }
        __syncthreads();

#pragma unroll
        for (int s = 0; s < 2; ++s) {
            const int koff = ((s * 4 + q) ^ xorv) * 8;
            bf16x8 af[4], bf[4];
#pragma unroll
            for (int i = 0; i < 4; ++i)
                af[i] = *(const bf16x8*)&As[(wm + i * 16 + ml) * 64 + koff];
#pragma unroll
            for (int j = 0; j < 4; ++j)
                bf[j] = *(const bf16x8*)&Bs[(wn + j * 16 + ml) * 64 + koff];
#pragma unroll
            for (int i = 0; i < 4; ++i)
#pragma unroll
                for (int j = 0; j < 4; ++j)
                    acc[i][j] = __builtin_amdgcn_mfma_f32_16x16x32_bf16(af[i], bf[j], acc[i][j], 0, 0, 0);
        }
        __syncthreads();
    }

    float vw[4];
#pragma unroll
    for (int j = 0; j < 4; ++j)
        vw[j] = v[n0 + wn + j * 16 + ml];

#pragma unroll
    for (int i = 0; i < 4; ++i) {
#pragma unroll
        for (int r = 0; r < 4; ++r) {
            float val = 0.f;
#pragma unroll
            for (int j = 0; j < 4; ++j)
                val += fast_tanh(acc[i][j][r]) * vw[j];
#pragma unroll
            for (int off = 8; off > 0; off >>= 1)
                val += __shfl_xor(val, off, 64);
            if (ml == 0)
                atomicAdd(&score[m0 + wm + i * 16 + q * 4 + r], val);
        }
    }
}

// ---------------- K3: softmax over compact scores -> COMPACT alpha ----------------
__global__ __launch_bounds__(256)
void softmax_compact(const float* __restrict__ score, const int* __restrict__ cnt,
                     float* __restrict__ alphac) {
    int b = blockIdx.x, t = threadIdx.x;
    int c = cnt[b];
    __shared__ float red[8];
    float sc[8];
    float mx = -1e30f;
#pragma unroll
    for (int i = 0; i < 8; ++i) {
        int k = i * 256 + t;
        sc[i] = (k < c) ? score[b * 2048 + k] : -1e30f;
        mx = fmaxf(mx, sc[i]);
    }
#pragma unroll
    for (int off = 32; off > 0; off >>= 1)
        mx = fmaxf(mx, __shfl_xor(mx, off, 64));
    if ((t & 63) == 0) red[t >> 6] = mx;
    __syncthreads();
    mx = fmaxf(fmaxf(red[0], red[1]), fmaxf(red[2], red[3]));
    float e[8], sum = 0.f;
#pragma unroll
    for (int i = 0; i < 8; ++i) {
        int k = i * 256 + t;
        e[i] = (k < c) ? __expf(sc[i] - mx) : 0.f;
        sum += e[i];
    }
#pragma unroll
    for (int off = 32; off > 0; off >>= 1)
        sum += __shfl_xor(sum, off, 64);
    if ((t & 63) == 0) red[4 + (t >> 6)] = sum;
    __syncthreads();
    float inv = 1.0f / (red[4] + red[5] + red[6] + red[7]);
#pragma unroll
    for (int i = 0; i < 8; ++i) {
        int k = i * 256 + t;
        if (k < c) alphac[b * 2048 + k] = e[i] * inv;
    }
}

// ---------------- K4: out[b,:] += sum_s alphac[s] * Ab[b,s,:]  (compact, bf16) -------
// grid 512 = 32 b x 16 s-segments; thread t covers 4 consecutive e via ushort4.
__global__ __launch_bounds__(256)
void wsum_bf16(const unsigned short* __restrict__ Ab, const float* __restrict__ alphac,
               const int* __restrict__ cnt, float* __restrict__ out) {
    int b   = blockIdx.x >> 4;
    int seg = blockIdx.x & 15;
    int t   = threadIdx.x;
    int c   = cnt[b];
    int per = (c + 15) >> 4;
    int s0  = seg * per;
    int s1  = min(s0 + per, c);
    const float* ap = alphac + b * 2048;
    const unsigned short* base = Ab + (size_t)b * 2048 * 1024 + t * 4;
    float a0 = 0.f, a1 = 0.f, a2 = 0.f, a3 = 0.f;
    for (int s = s0; s < s1; ++s) {
        float a = ap[s];
        ushort4 h = *(const ushort4*)(base + (size_t)s * 1024);
        a0 = __builtin_fmaf(a, __uint_as_float((unsigned)h.x << 16), a0);
        a1 = __builtin_fmaf(a, __uint_as_float((unsigned)h.y << 16), a1);
        a2 = __builtin_fmaf(a, __uint_as_float((unsigned)h.z << 16), a2);
        a3 = __builtin_fmaf(a, __uint_as_float((unsigned)h.w << 16), a3);
    }
    float* o = out + b * 1024 + t * 4;
    atomicAdd(o + 0, a0);
    atomicAdd(o + 1, a1);
    atomicAdd(o + 2, a2);
    atomicAdd(o + 3, a3);
}

// ================= fallback path (small ws): full-row fp32 pipeline =================
#define LDSS 40
__global__ __launch_bounds__(256)
void score_gemm_f32stage(const float* __restrict__ A, const unsigned short* __restrict__ Bw,
                         const float* __restrict__ v, float* __restrict__ score) {
    const int K = 1024;
    __shared__ __align__(16) unsigned short As[128][LDSS];
    __shared__ __align__(16) unsigned short Bs[128][LDSS];
    const int n0 = (int)blockIdx.x * 128;
    const int m0 = (int)blockIdx.y * 128;
    const int t = threadIdx.x, lane = t & 63, wave = t >> 6;
    const int wm = (wave & 1) * 64, wn = (wave >> 1) * 64;
    const int ml = lane & 15, q = lane >> 4;
    f32x4 acc[4][4];
#pragma unroll
    for (int i = 0; i < 4; ++i)
#pragma unroll
        for (int j = 0; j < 4; ++j) acc[i][j] = (f32x4){0.f,0.f,0.f,0.f};
    const int sr = t >> 3, sc = (t & 7) * 4;
    for (int kk = 0; kk < K; kk += 32) {
#pragma unroll
        for (int p = 0; p < 4; ++p) {
            int r = sr + p * 32;
            float4 va = *(const float4*)&A[(size_t)(m0 + r) * K + kk + sc];
            ushort4 h; h.x = f2bf(va.x); h.y = f2bf(va.y); h.z = f2bf(va.z); h.w = f2bf(va.w);
            *(ushort4*)&As[r][sc] = h;
            ushort4 vb = *(const ushort4*)&Bw[(size_t)(n0 + r) * K + kk + sc];
            *(ushort4*)&Bs[r][sc] = vb;
        }
        __syncthreads();
        bf16x8 af[4], bf[4];
#pragma unroll
        for (int i = 0; i < 4; ++i) af[i] = *(const bf16x8*)&As[wm + i * 16 + ml][q * 8];
#pragma unroll
        for (int j = 0; j < 4; ++j) bf[j] = *(const bf16x8*)&Bs[wn + j * 16 + ml][q * 8];
#pragma unroll
        for (int i = 0; i < 4; ++i)
#pragma unroll
            for (int j = 0; j < 4; ++j)
                acc[i][j] = __builtin_amdgcn_mfma_f32_16x16x32_bf16(af[i], bf[j], acc[i][j], 0, 0, 0);
        __syncthreads();
    }
    float vw[4];
#pragma unroll
    for (int j = 0; j < 4; ++j) vw[j] = v[n0 + wn + j * 16 + ml];
#pragma unroll
    for (int i = 0; i < 4; ++i)
#pragma unroll
        for (int r = 0; r < 4; ++r) {
            float val = 0.f;
#pragma unroll
            for (int j = 0; j < 4; ++j) val += fast_tanh(acc[i][j][r]) * vw[j];
#pragma unroll
            for (int off = 8; off > 0; off >>= 1) val += __shfl_xor(val, off, 64);
            if (ml == 0) atomicAdd(&score[m0 + wm + i * 16 + q * 4 + r], val);
        }
}

__global__ __launch_bounds__(256)
void softmax_kernel(const float* __restrict__ score, const int* __restrict__ mask,
                    float* __restrict__ alpha) {
    const int S = 2048;
    int b = blockIdx.x, t = threadIdx.x;
    __shared__ float red[8];
    float sc[8]; int vd[8];
    float mx = -1e30f;
#pragma unroll
    for (int i = 0; i < 8; ++i) {
        int s = i * 256 + t;
        vd[i] = mask[b * S + s];
        sc[i] = score[b * S + s];
        if (vd[i]) mx = fmaxf(mx, sc[i]);
    }
#pragma unroll
    for (int off = 32; off > 0; off >>= 1)
        mx = fmaxf(mx, __shfl_xor(mx, off, 64));
    if ((t & 63) == 0) red[t >> 6] = mx;
    __syncthreads();
    mx = fmaxf(fmaxf(red[0], red[1]), fmaxf(red[2], red[3]));
    float e[8]; float sum = 0.f;
#pragma unroll
    for (int i = 0; i < 8; ++i) {
        e[i] = vd[i] ? __expf(sc[i] - mx) : 0.f;
        sum += e[i];
    }
#pragma unroll
    for (int off = 32; off > 0; off >>= 1)
        sum += __shfl_xor(sum, off, 64);
    if ((t & 63) == 0) red[4 + (t >> 6)] = sum;
    __syncthreads();
    float inv = 1.0f / (red[4] + red[5] + red[6] + red[7]);
#pragma unroll
    for (int i = 0; i < 8; ++i)
        alpha[b * S + i * 256 + t] = e[i] * inv;
}

__global__ __launch_bounds__(256)
void wsum_kernel(const float* __restrict__ lhs, const float* __restrict__ alpha,
                 float* __restrict__ out) {
    const int S = 2048, E = 1024;
    int b = blockIdx.x >> 6;
    int seg = blockIdx.x & 63;
    int t = threadIdx.x;
    int s0 = seg * 32;
    const float* base = lhs + ((size_t)b * S + s0) * E + t * 4;
    const float* ap = alpha + b * S + s0;
    float4 acc = {0.f, 0.f, 0.f, 0.f};
#pragma unroll 4
    for (int s = 0; s < 32; ++s) {
        float a = ap[s];
        if (a != 0.f) {
            float4 x = *(const float4*)(base + (size_t)s * E);
            acc.x += a * x.x; acc.y += a * x.y; acc.z += a * x.z; acc.w += a * x.w;
        }
    }
    float* o = out + b * E + t * 4;
    atomicAdd(o + 0, acc.x);
    atomicAdd(o + 1, acc.y);
    atomicAdd(o + 2, acc.z);
    atomicAdd(o + 3, acc.w);
}

extern "C" void kernel_launch(void* const* d_in, const int* in_sizes, int n_in,
                              void* d_out, int out_size, void* d_ws, size_t ws_size,
                              hipStream_t stream) {
    const float* lhs  = (const float*)d_in[0];
    const int*   mask = (const int*)d_in[1];
    const float* W    = (const float*)d_in[2];
    const float* Um   = (const float*)d_in[3];
    const float* v    = (const float*)d_in[4];
    float* out = (float*)d_out;

    char* ws = (char*)d_ws;
    unsigned short* wsum  = (unsigned short*)ws;                      // 2 MB
    float* score          = (float*)(ws + 2048u * 1024u);             // 256 KB
    float* alphac         = (float*)(ws + 2304u * 1024u);             // 256 KB
    unsigned short* ridx  = (unsigned short*)(ws + 2560u * 1024u);    // 128 KB
    int* cnt              = (int*)(ws + 2688u * 1024u);               // 128 B
    unsigned short* Ab    = (unsigned short*)(ws + 2816u * 1024u);    // 128 MB
    const size_t need = 2816ull * 1024ull + 131072ull * 1024ull;

    prep_index<<<1056, 256, 0, stream>>>(W, Um, mask, wsum, score, out, ridx, cnt);
    if (ws_size >= need) {
        dim3 gg(512, 32);
        gather_convert<<<gg, 256, 0, stream>>>(lhs, ridx, cnt, Ab);
        score_gemm_bf16<<<4096, 256, 0, stream>>>(Ab, wsum, v, cnt, score);
        softmax_compact<<<32, 256, 0, stream>>>(score, cnt, alphac);
        wsum_bf16<<<512, 256, 0, stream>>>(Ab, alphac, cnt, out);
    } else {
        dim3 g1(8, 512);
        score_gemm_f32stage<<<g1, 256, 0, stream>>>(lhs, wsum, v, score);
        softmax_kernel<<<32, 256, 0, stream>>>(score, mask, alphac);
        wsum_kernel<<<2048, 256, 0, stream>>>(lhs, alphac, out);
    }
}

// Round 7
// 499.039 us; speedup vs baseline: 1.0453x; 1.0303x over previous
//
#include <hip/hip_runtime.h>
#include <hip/hip_bf16.h>

// Shapes (fixed): B=32, S=2048, E=1024, U=1024. M = B*S = 65536.
// score[m] = v . tanh( lhs[m,:] @ (W+U)^T )  -- bf16 MFMA GEMM on COMPACTED valid rows
//   GEMM v3: A staged via global_load_lds (swizzled LDS); B read DIRECTLY from L2
//   in k-major layout Bt[kc][n][8] (2 MB, XCD-L2-resident) -- halves LDS read traffic.
// out[b,:] = sum_s softmax(score)[s] * row[s]  (compact order)
//
// ws: Bt bf16 [0,2MB) | wsumrm bf16 [2MB,4MB) | score [4MB,+256KB) | alphac [+256KB)
//     | ridx u16 [4.5MB,+128KB) | cnt i32 [4.625MB,+128B) | Ab bf16 [5MB,+128MB)

typedef short bf16x8 __attribute__((ext_vector_type(8)));
typedef float f32x4  __attribute__((ext_vector_type(4)));
typedef unsigned short u16x8 __attribute__((ext_vector_type(8)));

static __device__ __forceinline__ unsigned short f2bf(float f) {
    unsigned int x = __float_as_uint(f);
    unsigned int r = x + 0x7FFFu + ((x >> 16) & 1u);   // RNE
    return (unsigned short)(r >> 16);
}

static __device__ __forceinline__ float fast_tanh(float x) {
    float e = __builtin_amdgcn_exp2f(x * 2.885390082f);   // e^{2x}
    float r = __builtin_amdgcn_rcpf(e + 1.0f);
    return __builtin_fmaf(-2.0f, r, 1.0f);
}

// ---------------- K0: [0..1023] Bt (k-major) + wsumrm = bf16(W+U), zero score/out
//                      [1024..1055] per-batch valid-row index scan ----------------
__global__ __launch_bounds__(256)
void prep_index(const float* __restrict__ W, const float* __restrict__ U,
                const int* __restrict__ mask,
                unsigned short* __restrict__ Bt, unsigned short* __restrict__ wsumrm,
                float* __restrict__ score, float* __restrict__ out,
                unsigned short* __restrict__ ridx, int* __restrict__ cnt) {
    __shared__ int sc[256];
    int blk = blockIdx.x, t = threadIdx.x;
    if (blk < 1024) {
        int g = blk * 256 + t;
        int i4 = g * 4;                       // 4 consecutive k of row n
        float4 w = *(const float4*)&W[i4];
        float4 u = *(const float4*)&U[i4];
        ushort4 h;
        h.x = f2bf(w.x + u.x); h.y = f2bf(w.y + u.y);
        h.z = f2bf(w.z + u.z); h.w = f2bf(w.w + u.w);
        *(ushort4*)&wsumrm[i4] = h;           // row-major copy (fallback path)
        int n  = i4 >> 10;
        int k0 = i4 & 1023;
        // Bt[kc][n][j]: elem offset = (k0>>3)*8192 + n*8 + (k0&7)
        *(ushort4*)&Bt[(size_t)(k0 >> 3) * 8192 + n * 8 + (k0 & 7)] = h;
        if (g < 65536) score[g] = 0.0f;
        if (g < 32768) out[g] = 0.0f;
    } else {
        int b = blk - 1024;
        const int* mrow = mask + b * 2048;
        int m[8], c = 0;
#pragma unroll
        for (int j = 0; j < 8; ++j) { m[j] = mrow[t * 8 + j]; c += (m[j] != 0); }
        sc[t] = c;
        __syncthreads();
        for (int off = 1; off < 256; off <<= 1) {
            int v = (t >= off) ? sc[t - off] : 0;
            __syncthreads();
            sc[t] += v;
            __syncthreads();
        }
        int base = sc[t] - c;
        unsigned short* rb = ridx + b * 2048;
#pragma unroll
        for (int j = 0; j < 8; ++j)
            if (m[j]) rb[base++] = (unsigned short)(t * 8 + j);
        if (t == 255) cnt[b] = sc[255];
    }
}

// ---------------- K1: gather valid rows -> bf16 compact (zero-pad to x128) ----------------
__global__ __launch_bounds__(256)
void gather_convert(const float* __restrict__ lhs, const unsigned short* __restrict__ ridx,
                    const int* __restrict__ cnt, unsigned short* __restrict__ Ab) {
    int b = blockIdx.y;
    int c = cnt[b];
    int cpad = (c + 127) & ~127;
    int r = blockIdx.x * 4 + (threadIdx.x >> 6);
    int lt = threadIdx.x & 63;
    if (r >= cpad) return;
    unsigned short* dst = Ab + ((size_t)b * 2048 + r) * 1024 + lt * 16;
    if (r < c) {
        int s = ridx[b * 2048 + r];
        const float* src = lhs + ((size_t)b * 2048 + s) * 1024 + lt * 16;
        float4 a0 = *(const float4*)(src + 0);
        float4 a1 = *(const float4*)(src + 4);
        float4 a2 = *(const float4*)(src + 8);
        float4 a3 = *(const float4*)(src + 12);
        u16x8 h0, h1;
        h0[0] = f2bf(a0.x); h0[1] = f2bf(a0.y); h0[2] = f2bf(a0.z); h0[3] = f2bf(a0.w);
        h0[4] = f2bf(a1.x); h0[5] = f2bf(a1.y); h0[6] = f2bf(a1.z); h0[7] = f2bf(a1.w);
        h1[0] = f2bf(a2.x); h1[1] = f2bf(a2.y); h1[2] = f2bf(a2.z); h1[3] = f2bf(a2.w);
        h1[4] = f2bf(a3.x); h1[5] = f2bf(a3.y); h1[6] = f2bf(a3.z); h1[7] = f2bf(a3.w);
        *(u16x8*)(dst + 0) = h0;
        *(u16x8*)(dst + 8) = h1;
    } else {
        u16x8 z = (u16x8){0,0,0,0,0,0,0,0};
        *(u16x8*)(dst + 0) = z;
        *(u16x8*)(dst + 8) = z;
    }
}

// ---------------- K2: score GEMM v3 -- A in LDS, B direct from L2 (k-major) ----------
__global__ __launch_bounds__(256)
void score_gemm_v3(const unsigned short* __restrict__ Ab,
                   const unsigned short* __restrict__ Bt,
                   const float* __restrict__ v, const int* __restrict__ cnt,
                   float* __restrict__ score) {
    const int K = 1024;
    __shared__ __align__(16) unsigned short As[128 * 64];   // 16 KB only

    const int bid    = (int)blockIdx.x;          // 0..4095, XCD swizzle
    const int group  = bid >> 6;
    const int mt     = (group << 3) + (bid & 7); // m-tile 0..511
    const int nI     = (bid >> 3) & 7;
    const int b      = mt >> 4;
    const int lm0    = (mt & 15) << 7;
    const int c      = cnt[b];
    if (lm0 >= ((c + 127) & ~127)) return;
    const int m0     = (b << 11) + lm0;
    const int n0     = nI << 7;

    const int t    = threadIdx.x;
    const int lane = t & 63;
    const int wave = t >> 6;
    const int wm   = (wave & 1) * 64;
    const int wn   = (wave >> 1) * 64;
    const int ml   = lane & 15;
    const int q    = lane >> 4;
    const int xorv = ml & 7;

    f32x4 acc[4][4];
#pragma unroll
    for (int i = 0; i < 4; ++i)
#pragma unroll
        for (int j = 0; j < 4; ++j)
            acc[i][j] = (f32x4){0.f, 0.f, 0.f, 0.f};

    // A staging: 128x64 bf16 = 1024 x 16B chunks; slot l holds chunk (l&7)^(row&7).
    const unsigned short* gA[4];
    unsigned short* lA[4];
#pragma unroll
    for (int p = 0; p < 4; ++p) {
        int l   = p * 256 + wave * 64 + lane;
        int row = l >> 3;
        int kc  = (l & 7) ^ (row & 7);
        gA[p] = Ab + (size_t)(m0 + row) * K + kc * 8;
        lA[p] = &As[(p * 4 + wave) * 512];
    }

    // B pointers: Bt[kc][n][8]; frag j reads n = n0+wn+j*16+ml, k-chunk (kk/8 + s*4 + q).
    const unsigned short* bp[4];
#pragma unroll
    for (int j = 0; j < 4; ++j)
        bp[j] = Bt + (size_t)q * 8192 + (n0 + wn + j * 16 + ml) * 8;

    for (int kk = 0; kk < K; kk += 64) {
#pragma unroll
        for (int p = 0; p < 4; ++p) {
            __builtin_amdgcn_global_load_lds((const __attribute__((address_space(1))) unsigned int*)gA[p],
                                             (__attribute__((address_space(3))) unsigned int*)lA[p], 16, 0, 0);
            gA[p] += 64;
        }
        __syncthreads();

#pragma unroll
        for (int s = 0; s < 2; ++s) {
            bf16x8 bf[4];
#pragma unroll
            for (int j = 0; j < 4; ++j)
                bf[j] = *(const bf16x8*)(bp[j] + (size_t)s * 32768);   // L2-hit, no LDS
            const int koff = ((s * 4 + q) ^ xorv) * 8;
            bf16x8 af[4];
#pragma unroll
            for (int i = 0; i < 4; ++i)
                af[i] = *(const bf16x8*)&As[(wm + i * 16 + ml) * 64 + koff];
#pragma unroll
            for (int i = 0; i < 4; ++i)
#pragma unroll
                for (int j = 0; j < 4; ++j)
                    acc[i][j] = __builtin_amdgcn_mfma_f32_16x16x32_bf16(af[i], bf[j], acc[i][j], 0, 0, 0);
        }
#pragma unroll
        for (int j = 0; j < 4; ++j)
            bp[j] += 65536;                     // next 8 k-chunks
        __syncthreads();
    }

    // score[m] += sum_n v[n]*tanh(P[m,n]).  D layout: col=lane&15, row=q*4+reg.
    float vw[4];
#pragma unroll
    for (int j = 0; j < 4; ++j)
        vw[j] = v[n0 + wn + j * 16 + ml];

#pragma unroll
    for (int i = 0; i < 4; ++i) {
#pragma unroll
        for (int r = 0; r < 4; ++r) {
            float val = 0.f;
#pragma unroll
            for (int j = 0; j < 4; ++j)
                val += fast_tanh(acc[i][j][r]) * vw[j];
#pragma unroll
            for (int off = 8; off > 0; off >>= 1)
                val += __shfl_xor(val, off, 64);
            if (ml == 0)
                atomicAdd(&score[m0 + wm + i * 16 + q * 4 + r], val);
        }
    }
}

// ---------------- K3: softmax over compact scores -> COMPACT alpha ----------------
__global__ __launch_bounds__(256)
void softmax_compact(const float* __restrict__ score, const int* __restrict__ cnt,
                     float* __restrict__ alphac) {
    int b = blockIdx.x, t = threadIdx.x;
    int c = cnt[b];
    __shared__ float red[8];
    float sc[8];
    float mx = -1e30f;
#pragma unroll
    for (int i = 0; i < 8; ++i) {
        int k = i * 256 + t;
        sc[i] = (k < c) ? score[b * 2048 + k] : -1e30f;
        mx = fmaxf(mx, sc[i]);
    }
#pragma unroll
    for (int off = 32; off > 0; off >>= 1)
        mx = fmaxf(mx, __shfl_xor(mx, off, 64));
    if ((t & 63) == 0) red[t >> 6] = mx;
    __syncthreads();
    mx = fmaxf(fmaxf(red[0], red[1]), fmaxf(red[2], red[3]));
    float e[8], sum = 0.f;
#pragma unroll
    for (int i = 0; i < 8; ++i) {
        int k = i * 256 + t;
        e[i] = (k < c) ? __expf(sc[i] - mx) : 0.f;
        sum += e[i];
    }
#pragma unroll
    for (int off = 32; off > 0; off >>= 1)
        sum += __shfl_xor(sum, off, 64);
    if ((t & 63) == 0) red[4 + (t >> 6)] = sum;
    __syncthreads();
    float inv = 1.0f / (red[4] + red[5] + red[6] + red[7]);
#pragma unroll
    for (int i = 0; i < 8; ++i) {
        int k = i * 256 + t;
        if (k < c) alphac[b * 2048 + k] = e[i] * inv;
    }
}

// ---------------- K4: out[b,:] += sum_s alphac[s] * Ab[b,s,:]  (compact, bf16) -------
__global__ __launch_bounds__(256)
void wsum_bf16(const unsigned short* __restrict__ Ab, const float* __restrict__ alphac,
               const int* __restrict__ cnt, float* __restrict__ out) {
    int b   = blockIdx.x >> 4;
    int seg = blockIdx.x & 15;
    int t   = threadIdx.x;
    int c   = cnt[b];
    int per = (c + 15) >> 4;
    int s0  = seg * per;
    int s1  = min(s0 + per, c);
    const float* ap = alphac + b * 2048;
    const unsigned short* base = Ab + (size_t)b * 2048 * 1024 + t * 4;
    float a0 = 0.f, a1 = 0.f, a2 = 0.f, a3 = 0.f;
    for (int s = s0; s < s1; ++s) {
        float a = ap[s];
        ushort4 h = *(const ushort4*)(base + (size_t)s * 1024);
        a0 = __builtin_fmaf(a, __uint_as_float((unsigned)h.x << 16), a0);
        a1 = __builtin_fmaf(a, __uint_as_float((unsigned)h.y << 16), a1);
        a2 = __builtin_fmaf(a, __uint_as_float((unsigned)h.z << 16), a2);
        a3 = __builtin_fmaf(a, __uint_as_float((unsigned)h.w << 16), a3);
    }
    float* o = out + b * 1024 + t * 4;
    atomicAdd(o + 0, a0);
    atomicAdd(o + 1, a1);
    atomicAdd(o + 2, a2);
    atomicAdd(o + 3, a3);
}

// ================= fallback path (small ws): full-row fp32 pipeline =================
#define LDSS 40
__global__ __launch_bounds__(256)
void score_gemm_f32stage(const float* __restrict__ A, const unsigned short* __restrict__ Bw,
                         const float* __restrict__ v, float* __restrict__ score) {
    const int K = 1024;
    __shared__ __align__(16) unsigned short As[128][LDSS];
    __shared__ __align__(16) unsigned short Bs[128][LDSS];
    const int n0 = (int)blockIdx.x * 128;
    const int m0 = (int)blockIdx.y * 128;
    const int t = threadIdx.x, lane = t & 63, wave = t >> 6;
    const int wm = (wave & 1) * 64, wn = (wave >> 1) * 64;
    const int ml = lane & 15, q = lane >> 4;
    f32x4 acc[4][4];
#pragma unroll
    for (int i = 0; i < 4; ++i)
#pragma unroll
        for (int j = 0; j < 4; ++j) acc[i][j] = (f32x4){0.f,0.f,0.f,0.f};
    const int sr = t >> 3, sc = (t & 7) * 4;
    for (int kk = 0; kk < K; kk += 32) {
#pragma unroll
        for (int p = 0; p < 4; ++p) {
            int r = sr + p * 32;
            float4 va = *(const float4*)&A[(size_t)(m0 + r) * K + kk + sc];
            ushort4 h; h.x = f2bf(va.x); h.y = f2bf(va.y); h.z = f2bf(va.z); h.w = f2bf(va.w);
            *(ushort4*)&As[r][sc] = h;
            ushort4 vb = *(const ushort4*)&Bw[(size_t)(n0 + r) * K + kk + sc];
            *(ushort4*)&Bs[r][sc] = vb;
        }
        __syncthreads();
        bf16x8 af[4], bf[4];
#pragma unroll
        for (int i = 0; i < 4; ++i) af[i] = *(const bf16x8*)&As[wm + i * 16 + ml][q * 8];
#pragma unroll
        for (int j = 0; j < 4; ++j) bf[j] = *(const bf16x8*)&Bs[wn + j * 16 + ml][q * 8];
#pragma unroll
        for (int i = 0; i < 4; ++i)
#pragma unroll
            for (int j = 0; j < 4; ++j)
                acc[i][j] = __builtin_amdgcn_mfma_f32_16x16x32_bf16(af[i], bf[j], acc[i][j], 0, 0, 0);
        __syncthreads();
    }
    float vw[4];
#pragma unroll
    for (int j = 0; j < 4; ++j) vw[j] = v[n0 + wn + j * 16 + ml];
#pragma unroll
    for (int i = 0; i < 4; ++i)
#pragma unroll
        for (int r = 0; r < 4; ++r) {
            float val = 0.f;
#pragma unroll
            for (int j = 0; j < 4; ++j) val += fast_tanh(acc[i][j][r]) * vw[j];
#pragma unroll
            for (int off = 8; off > 0; off >>= 1) val += __shfl_xor(val, off, 64);
            if (ml == 0) atomicAdd(&score[m0 + wm + i * 16 + q * 4 + r], val);
        }
}

__global__ __launch_bounds__(256)
void softmax_kernel(const float* __restrict__ score, const int* __restrict__ mask,
                    float* __restrict__ alpha) {
    const int S = 2048;
    int b = blockIdx.x, t = threadIdx.x;
    __shared__ float red[8];
    float sc[8]; int vd[8];
    float mx = -1e30f;
#pragma unroll
    for (int i = 0; i < 8; ++i) {
        int s = i * 256 + t;
        vd[i] = mask[b * S + s];
        sc[i] = score[b * S + s];
        if (vd[i]) mx = fmaxf(mx, sc[i]);
    }
#pragma unroll
    for (int off = 32; off > 0; off >>= 1)
        mx = fmaxf(mx, __shfl_xor(mx, off, 64));
    if ((t & 63) == 0) red[t >> 6] = mx;
    __syncthreads();
    mx = fmaxf(fmaxf(red[0], red[1]), fmaxf(red[2], red[3]));
    float e[8]; float sum = 0.f;
#pragma unroll
    for (int i = 0; i < 8; ++i) {
        e[i] = vd[i] ? __expf(sc[i] - mx) : 0.f;
        sum += e[i];
    }
#pragma unroll
    for (int off = 32; off > 0; off >>= 1)
        sum += __shfl_xor(sum, off, 64);
    if ((t & 63) == 0) red[4 + (t >> 6)] = sum;
    __syncthreads();
    float inv = 1.0f / (red[4] + red[5] + red[6] + red[7]);
#pragma unroll
    for (int i = 0; i < 8; ++i)
        alpha[b * S + i * 256 + t] = e[i] * inv;
}

__global__ __launch_bounds__(256)
void wsum_kernel(const float* __restrict__ lhs, const float* __restrict__ alpha,
                 float* __restrict__ out) {
    const int S = 2048, E = 1024;
    int b = blockIdx.x >> 6;
    int seg = blockIdx.x & 63;
    int t = threadIdx.x;
    int s0 = seg * 32;
    const float* base = lhs + ((size_t)b * S + s0) * E + t * 4;
    const float* ap = alpha + b * S + s0;
    float4 acc = {0.f, 0.f, 0.f, 0.f};
#pragma unroll 4
    for (int s = 0; s < 32; ++s) {
        float a = ap[s];
        if (a != 0.f) {
            float4 x = *(const float4*)(base + (size_t)s * E);
            acc.x += a * x.x; acc.y += a * x.y; acc.z += a * x.z; acc.w += a * x.w;
        }
    }
    float* o = out + b * E + t * 4;
    atomicAdd(o + 0, acc.x);
    atomicAdd(o + 1, acc.y);
    atomicAdd(o + 2, acc.z);
    atomicAdd(o + 3, acc.w);
}

extern "C" void kernel_launch(void* const* d_in, const int* in_sizes, int n_in,
                              void* d_out, int out_size, void* d_ws, size_t ws_size,
                              hipStream_t stream) {
    const float* lhs  = (const float*)d_in[0];
    const int*   mask = (const int*)d_in[1];
    const float* W    = (const float*)d_in[2];
    const float* Um   = (const float*)d_in[3];
    const float* v    = (const float*)d_in[4];
    float* out = (float*)d_out;

    char* ws = (char*)d_ws;
    unsigned short* Bt     = (unsigned short*)ws;                      // 2 MB (k-major)
    unsigned short* wsumrm = (unsigned short*)(ws + 2048u * 1024u);    // 2 MB (row-major)
    float* score           = (float*)(ws + 4096u * 1024u);             // 256 KB
    float* alphac          = (float*)(ws + 4352u * 1024u);             // 256 KB
    unsigned short* ridx   = (unsigned short*)(ws + 4608u * 1024u);    // 128 KB
    int* cnt               = (int*)(ws + 4736u * 1024u);               // 128 B
    unsigned short* Ab     = (unsigned short*)(ws + 5120u * 1024u);    // 128 MB
    const size_t need = 5120ull * 1024ull + 131072ull * 1024ull;

    prep_index<<<1056, 256, 0, stream>>>(W, Um, mask, Bt, wsumrm, score, out, ridx, cnt);
    if (ws_size >= need) {
        dim3 gg(512, 32);
        gather_convert<<<gg, 256, 0, stream>>>(lhs, ridx, cnt, Ab);
        score_gemm_v3<<<4096, 256, 0, stream>>>(Ab, Bt, v, cnt, score);
        softmax_compact<<<32, 256, 0, stream>>>(score, cnt, alphac);
        wsum_bf16<<<512, 256, 0, stream>>>(Ab, alphac, cnt, out);
    } else {
        dim3 g1(8, 512);
        score_gemm_f32stage<<<g1, 256, 0, stream>>>(lhs, wsumrm, v, score);
        softmax_kernel<<<32, 256, 0, stream>>>(score, mask, alphac);
        wsum_kernel<<<2048, 256, 0, stream>>>(lhs, alphac, out);
    }
}

// Round 8
// 497.451 us; speedup vs baseline: 1.0486x; 1.0032x over previous
//
#include <hip/hip_runtime.h>
#include <hip/hip_bf16.h>

// Shapes (fixed): B=32, S=2048, E=1024, U=1024. M = B*S = 65536.
// score[m] = v . tanh( lhs[m,:] @ (W+U)^T )  -- bf16 MFMA GEMM on COMPACTED valid rows
//   GEMM: A staged via global_load_lds (swizzled LDS); B direct from L2 (k-major Bt).
// out[b,:] = sum_s softmax(score)[s] * row[s]  -- fused softmax+wsum (compact order)
//
// ws: Bt bf16 [0,2MB) | wsumrm bf16 [2MB,4MB) | score [4MB,+256KB) | alphac [+256KB)
//     | ridx u16 [4.5MB,+128KB) | cnt i32 [4.625MB,+128B) | Ab bf16 [5MB,+128MB)

typedef short bf16x8 __attribute__((ext_vector_type(8)));
typedef float f32x4  __attribute__((ext_vector_type(4)));
typedef unsigned short u16x8 __attribute__((ext_vector_type(8)));

static __device__ __forceinline__ unsigned short f2bf(float f) {
    unsigned int x = __float_as_uint(f);
    unsigned int r = x + 0x7FFFu + ((x >> 16) & 1u);   // RNE
    return (unsigned short)(r >> 16);
}

static __device__ __forceinline__ float fast_tanh(float x) {
    float e = __builtin_amdgcn_exp2f(x * 2.885390082f);   // e^{2x}
    float r = __builtin_amdgcn_rcpf(e + 1.0f);
    return __builtin_fmaf(-2.0f, r, 1.0f);
}

// ---------------- K0: [0..1023] Bt (k-major) + wsumrm = bf16(W+U), zero score/out
//                      [1024..1055] per-batch valid-row index scan ----------------
__global__ __launch_bounds__(256)
void prep_index(const float* __restrict__ W, const float* __restrict__ U,
                const int* __restrict__ mask,
                unsigned short* __restrict__ Bt, unsigned short* __restrict__ wsumrm,
                float* __restrict__ score, float* __restrict__ out,
                unsigned short* __restrict__ ridx, int* __restrict__ cnt) {
    __shared__ int sc[256];
    int blk = blockIdx.x, t = threadIdx.x;
    if (blk < 1024) {
        int g = blk * 256 + t;
        int i4 = g * 4;                       // 4 consecutive k of row n
        float4 w = *(const float4*)&W[i4];
        float4 u = *(const float4*)&U[i4];
        ushort4 h;
        h.x = f2bf(w.x + u.x); h.y = f2bf(w.y + u.y);
        h.z = f2bf(w.z + u.z); h.w = f2bf(w.w + u.w);
        *(ushort4*)&wsumrm[i4] = h;           // row-major copy (fallback path)
        int n  = i4 >> 10;
        int k0 = i4 & 1023;
        // Bt[kc][n][j]: elem offset = (k0>>3)*8192 + n*8 + (k0&7)
        *(ushort4*)&Bt[(size_t)(k0 >> 3) * 8192 + n * 8 + (k0 & 7)] = h;
        if (g < 65536) score[g] = 0.0f;
        if (g < 32768) out[g] = 0.0f;
    } else {
        int b = blk - 1024;
        const int* mrow = mask + b * 2048;
        int m[8], c = 0;
#pragma unroll
        for (int j = 0; j < 8; ++j) { m[j] = mrow[t * 8 + j]; c += (m[j] != 0); }
        sc[t] = c;
        __syncthreads();
        for (int off = 1; off < 256; off <<= 1) {
            int v = (t >= off) ? sc[t - off] : 0;
            __syncthreads();
            sc[t] += v;
            __syncthreads();
        }
        int base = sc[t] - c;
        unsigned short* rb = ridx + b * 2048;
#pragma unroll
        for (int j = 0; j < 8; ++j)
            if (m[j]) rb[base++] = (unsigned short)(t * 8 + j);
        if (t == 255) cnt[b] = sc[255];
    }
}

// ---------------- K1: gather valid rows -> bf16 compact (zero-pad to x128) ----------------
__global__ __launch_bounds__(256)
void gather_convert(const float* __restrict__ lhs, const unsigned short* __restrict__ ridx,
                    const int* __restrict__ cnt, unsigned short* __restrict__ Ab) {
    int b = blockIdx.y;
    int c = cnt[b];
    int cpad = (c + 127) & ~127;
    int r = blockIdx.x * 4 + (threadIdx.x >> 6);
    int lt = threadIdx.x & 63;
    if (r >= cpad) return;
    unsigned short* dst = Ab + ((size_t)b * 2048 + r) * 1024 + lt * 16;
    if (r < c) {
        int s = ridx[b * 2048 + r];
        const float* src = lhs + ((size_t)b * 2048 + s) * 1024 + lt * 16;
        float4 a0 = *(const float4*)(src + 0);
        float4 a1 = *(const float4*)(src + 4);
        float4 a2 = *(const float4*)(src + 8);
        float4 a3 = *(const float4*)(src + 12);
        u16x8 h0, h1;
        h0[0] = f2bf(a0.x); h0[1] = f2bf(a0.y); h0[2] = f2bf(a0.z); h0[3] = f2bf(a0.w);
        h0[4] = f2bf(a1.x); h0[5] = f2bf(a1.y); h0[6] = f2bf(a1.z); h0[7] = f2bf(a1.w);
        h1[0] = f2bf(a2.x); h1[1] = f2bf(a2.y); h1[2] = f2bf(a2.z); h1[3] = f2bf(a2.w);
        h1[4] = f2bf(a3.x); h1[5] = f2bf(a3.y); h1[6] = f2bf(a3.z); h1[7] = f2bf(a3.w);
        *(u16x8*)(dst + 0) = h0;
        *(u16x8*)(dst + 8) = h1;
    } else {
        u16x8 z = (u16x8){0,0,0,0,0,0,0,0};
        *(u16x8*)(dst + 0) = z;
        *(u16x8*)(dst + 8) = z;
    }
}

// ---------------- K2: score GEMM -- A in LDS (swizzled), B direct from L2 (k-major) ---
__global__ __launch_bounds__(256)
void score_gemm_v3(const unsigned short* __restrict__ Ab,
                   const unsigned short* __restrict__ Bt,
                   const float* __restrict__ v, const int* __restrict__ cnt,
                   float* __restrict__ score) {
    const int K = 1024;
    __shared__ __align__(16) unsigned short As[128 * 64];   // 16 KB

    const int bid    = (int)blockIdx.x;          // 0..4095, XCD swizzle
    const int group  = bid >> 6;
    const int mt     = (group << 3) + (bid & 7); // m-tile 0..511
    const int nI     = (bid >> 3) & 7;
    const int b      = mt >> 4;
    const int lm0    = (mt & 15) << 7;
    const int c      = cnt[b];
    if (lm0 >= ((c + 127) & ~127)) return;
    const int m0     = (b << 11) + lm0;
    const int n0     = nI << 7;

    const int t    = threadIdx.x;
    const int lane = t & 63;
    const int wave = t >> 6;
    const int wm   = (wave & 1) * 64;
    const int wn   = (wave >> 1) * 64;
    const int ml   = lane & 15;
    const int q    = lane >> 4;
    const int xorv = ml & 7;

    f32x4 acc[4][4];
#pragma unroll
    for (int i = 0; i < 4; ++i)
#pragma unroll
        for (int j = 0; j < 4; ++j)
            acc[i][j] = (f32x4){0.f, 0.f, 0.f, 0.f};

    // A staging: 128x64 bf16 = 1024 x 16B chunks; slot l holds chunk (l&7)^(row&7).
    const unsigned short* gA[4];
    unsigned short* lA[4];
#pragma unroll
    for (int p = 0; p < 4; ++p) {
        int l   = p * 256 + wave * 64 + lane;
        int row = l >> 3;
        int kc  = (l & 7) ^ (row & 7);
        gA[p] = Ab + (size_t)(m0 + row) * K + kc * 8;
        lA[p] = &As[(p * 4 + wave) * 512];
    }

    // B pointers: Bt[kc][n][8]; frag j reads n = n0+wn+j*16+ml, k-chunk (kk/8 + s*4 + q).
    const unsigned short* bp[4];
#pragma unroll
    for (int j = 0; j < 4; ++j)
        bp[j] = Bt + (size_t)q * 8192 + (n0 + wn + j * 16 + ml) * 8;

    for (int kk = 0; kk < K; kk += 64) {
#pragma unroll
        for (int p = 0; p < 4; ++p) {
            __builtin_amdgcn_global_load_lds((const __attribute__((address_space(1))) unsigned int*)gA[p],
                                             (__attribute__((address_space(3))) unsigned int*)lA[p], 16, 0, 0);
            gA[p] += 64;
        }
        __syncthreads();

#pragma unroll
        for (int s = 0; s < 2; ++s) {
            bf16x8 bf[4];
#pragma unroll
            for (int j = 0; j < 4; ++j)
                bf[j] = *(const bf16x8*)(bp[j] + (size_t)s * 32768);   // L2-hit, no LDS
            const int koff = ((s * 4 + q) ^ xorv) * 8;
            bf16x8 af[4];
#pragma unroll
            for (int i = 0; i < 4; ++i)
                af[i] = *(const bf16x8*)&As[(wm + i * 16 + ml) * 64 + koff];
#pragma unroll
            for (int i = 0; i < 4; ++i)
#pragma unroll
                for (int j = 0; j < 4; ++j)
                    acc[i][j] = __builtin_amdgcn_mfma_f32_16x16x32_bf16(af[i], bf[j], acc[i][j], 0, 0, 0);
        }
#pragma unroll
        for (int j = 0; j < 4; ++j)
            bp[j] += 65536;                     // next 8 k-chunks
        __syncthreads();
    }

    // score[m] += sum_n v[n]*tanh(P[m,n]).  D layout: col=lane&15, row=q*4+reg.
    float vw[4];
#pragma unroll
    for (int j = 0; j < 4; ++j)
        vw[j] = v[n0 + wn + j * 16 + ml];

#pragma unroll
    for (int i = 0; i < 4; ++i) {
#pragma unroll
        for (int r = 0; r < 4; ++r) {
            float val = 0.f;
#pragma unroll
            for (int j = 0; j < 4; ++j)
                val += fast_tanh(acc[i][j][r]) * vw[j];
#pragma unroll
            for (int off = 8; off > 0; off >>= 1)
                val += __shfl_xor(val, off, 64);
            if (ml == 0)
                atomicAdd(&score[m0 + wm + i * 16 + q * 4 + r], val);
        }
    }
}

// ---------------- K3: FUSED softmax + weighted sum (compact, bf16) ----------------
// grid 512 = 32 b x 16 segments. Each block redundantly computes its batch's softmax
// (bitwise-identical reduction per block) into LDS, then does its wsum segment.
__global__ __launch_bounds__(256)
void softmax_wsum(const float* __restrict__ score, const int* __restrict__ cnt,
                  const unsigned short* __restrict__ Ab, float* __restrict__ out) {
    __shared__ float red[8];
    __shared__ float al[2048];
    int b   = blockIdx.x >> 4;
    int seg = blockIdx.x & 15;
    int t   = threadIdx.x;
    int c   = cnt[b];

    // --- softmax over compact scores (same order in every block of this batch) ---
    float sc[8];
    float mx = -1e30f;
#pragma unroll
    for (int i = 0; i < 8; ++i) {
        int k = i * 256 + t;
        sc[i] = (k < c) ? score[b * 2048 + k] : -1e30f;
        mx = fmaxf(mx, sc[i]);
    }
#pragma unroll
    for (int off = 32; off > 0; off >>= 1)
        mx = fmaxf(mx, __shfl_xor(mx, off, 64));
    if ((t & 63) == 0) red[t >> 6] = mx;
    __syncthreads();
    mx = fmaxf(fmaxf(red[0], red[1]), fmaxf(red[2], red[3]));
    float e[8], sum = 0.f;
#pragma unroll
    for (int i = 0; i < 8; ++i) {
        int k = i * 256 + t;
        e[i] = (k < c) ? __expf(sc[i] - mx) : 0.f;
        sum += e[i];
    }
#pragma unroll
    for (int off = 32; off > 0; off >>= 1)
        sum += __shfl_xor(sum, off, 64);
    if ((t & 63) == 0) red[4 + (t >> 6)] = sum;
    __syncthreads();
    float inv = 1.0f / (red[4] + red[5] + red[6] + red[7]);
#pragma unroll
    for (int i = 0; i < 8; ++i)
        al[i * 256 + t] = e[i] * inv;
    __syncthreads();

    // --- weighted sum over this block's segment (alpha from LDS broadcast) ---
    int per = (c + 15) >> 4;
    int s0  = seg * per;
    int s1  = min(s0 + per, c);
    const unsigned short* base = Ab + (size_t)b * 2048 * 1024 + t * 4;
    float a0 = 0.f, a1 = 0.f, a2 = 0.f, a3 = 0.f;
    for (int s = s0; s < s1; ++s) {
        float a = al[s];
        ushort4 h = *(const ushort4*)(base + (size_t)s * 1024);
        a0 = __builtin_fmaf(a, __uint_as_float((unsigned)h.x << 16), a0);
        a1 = __builtin_fmaf(a, __uint_as_float((unsigned)h.y << 16), a1);
        a2 = __builtin_fmaf(a, __uint_as_float((unsigned)h.z << 16), a2);
        a3 = __builtin_fmaf(a, __uint_as_float((unsigned)h.w << 16), a3);
    }
    float* o = out + b * 1024 + t * 4;
    atomicAdd(o + 0, a0);
    atomicAdd(o + 1, a1);
    atomicAdd(o + 2, a2);
    atomicAdd(o + 3, a3);
}

// ================= fallback path (small ws): full-row fp32 pipeline =================
#define LDSS 40
__global__ __launch_bounds__(256)
void score_gemm_f32stage(const float* __restrict__ A, const unsigned short* __restrict__ Bw,
                         const float* __restrict__ v, float* __restrict__ score) {
    const int K = 1024;
    __shared__ __align__(16) unsigned short As[128][LDSS];
    __shared__ __align__(16) unsigned short Bs[128][LDSS];
    const int n0 = (int)blockIdx.x * 128;
    const int m0 = (int)blockIdx.y * 128;
    const int t = threadIdx.x, lane = t & 63, wave = t >> 6;
    const int wm = (wave & 1) * 64, wn = (wave >> 1) * 64;
    const int ml = lane & 15, q = lane >> 4;
    f32x4 acc[4][4];
#pragma unroll
    for (int i = 0; i < 4; ++i)
#pragma unroll
        for (int j = 0; j < 4; ++j) acc[i][j] = (f32x4){0.f,0.f,0.f,0.f};
    const int sr = t >> 3, sc = (t & 7) * 4;
    for (int kk = 0; kk < K; kk += 32) {
#pragma unroll
        for (int p = 0; p < 4; ++p) {
            int r = sr + p * 32;
            float4 va = *(const float4*)&A[(size_t)(m0 + r) * K + kk + sc];
            ushort4 h; h.x = f2bf(va.x); h.y = f2bf(va.y); h.z = f2bf(va.z); h.w = f2bf(va.w);
            *(ushort4*)&As[r][sc] = h;
            ushort4 vb = *(const ushort4*)&Bw[(size_t)(n0 + r) * K + kk + sc];
            *(ushort4*)&Bs[r][sc] = vb;
        }
        __syncthreads();
        bf16x8 af[4], bf[4];
#pragma unroll
        for (int i = 0; i < 4; ++i) af[i] = *(const bf16x8*)&As[wm + i * 16 + ml][q * 8];
#pragma unroll
        for (int j = 0; j < 4; ++j) bf[j] = *(const bf16x8*)&Bs[wn + j * 16 + ml][q * 8];
#pragma unroll
        for (int i = 0; i < 4; ++i)
#pragma unroll
            for (int j = 0; j < 4; ++j)
                acc[i][j] = __builtin_amdgcn_mfma_f32_16x16x32_bf16(af[i], bf[j], acc[i][j], 0, 0, 0);
        __syncthreads();
    }
    float vw[4];
#pragma unroll
    for (int j = 0; j < 4; ++j) vw[j] = v[n0 + wn + j * 16 + ml];
#pragma unroll
    for (int i = 0; i < 4; ++i)
#pragma unroll
        for (int r = 0; r < 4; ++r) {
            float val = 0.f;
#pragma unroll
            for (int j = 0; j < 4; ++j) val += fast_tanh(acc[i][j][r]) * vw[j];
#pragma unroll
            for (int off = 8; off > 0; off >>= 1) val += __shfl_xor(val, off, 64);
            if (ml == 0) atomicAdd(&score[m0 + wm + i * 16 + q * 4 + r], val);
        }
}

__global__ __launch_bounds__(256)
void softmax_kernel(const float* __restrict__ score, const int* __restrict__ mask,
                    float* __restrict__ alpha) {
    const int S = 2048;
    int b = blockIdx.x, t = threadIdx.x;
    __shared__ float red[8];
    float sc[8]; int vd[8];
    float mx = -1e30f;
#pragma unroll
    for (int i = 0; i < 8; ++i) {
        int s = i * 256 + t;
        vd[i] = mask[b * S + s];
        sc[i] = score[b * S + s];
        if (vd[i]) mx = fmaxf(mx, sc[i]);
    }
#pragma unroll
    for (int off = 32; off > 0; off >>= 1)
        mx = fmaxf(mx, __shfl_xor(mx, off, 64));
    if ((t & 63) == 0) red[t >> 6] = mx;
    __syncthreads();
    mx = fmaxf(fmaxf(red[0], red[1]), fmaxf(red[2], red[3]));
    float e[8]; float sum = 0.f;
#pragma unroll
    for (int i = 0; i < 8; ++i) {
        e[i] = vd[i] ? __expf(sc[i] - mx) : 0.f;
        sum += e[i];
    }
#pragma unroll
    for (int off = 32; off > 0; off >>= 1)
        sum += __shfl_xor(sum, off, 64);
    if ((t & 63) == 0) red[4 + (t >> 6)] = sum;
    __syncthreads();
    float inv = 1.0f / (red[4] + red[5] + red[6] + red[7]);
#pragma unroll
    for (int i = 0; i < 8; ++i)
        alpha[b * S + i * 256 + t] = e[i] * inv;
}

__global__ __launch_bounds__(256)
void wsum_kernel(const float* __restrict__ lhs, const float* __restrict__ alpha,
                 float* __restrict__ out) {
    const int S = 2048, E = 1024;
    int b = blockIdx.x >> 6;
    int seg = blockIdx.x & 63;
    int t = threadIdx.x;
    int s0 = seg * 32;
    const float* base = lhs + ((size_t)b * S + s0) * E + t * 4;
    const float* ap = alpha + b * S + s0;
    float4 acc = {0.f, 0.f, 0.f, 0.f};
#pragma unroll 4
    for (int s = 0; s < 32; ++s) {
        float a = ap[s];
        if (a != 0.f) {
            float4 x = *(const float4*)(base + (size_t)s * E);
            acc.x += a * x.x; acc.y += a * x.y; acc.z += a * x.z; acc.w += a * x.w;
        }
    }
    float* o = out + b * E + t * 4;
    atomicAdd(o + 0, acc.x);
    atomicAdd(o + 1, acc.y);
    atomicAdd(o + 2, acc.z);
    atomicAdd(o + 3, acc.w);
}

extern "C" void kernel_launch(void* const* d_in, const int* in_sizes, int n_in,
                              void* d_out, int out_size, void* d_ws, size_t ws_size,
                              hipStream_t stream) {
    const float* lhs  = (const float*)d_in[0];
    const int*   mask = (const int*)d_in[1];
    const float* W    = (const float*)d_in[2];
    const float* Um   = (const float*)d_in[3];
    const float* v    = (const float*)d_in[4];
    float* out = (float*)d_out;

    char* ws = (char*)d_ws;
    unsigned short* Bt     = (unsigned short*)ws;                      // 2 MB (k-major)
    unsigned short* wsumrm = (unsigned short*)(ws + 2048u * 1024u);    // 2 MB (row-major)
    float* score           = (float*)(ws + 4096u * 1024u);             // 256 KB
    float* alphac          = (float*)(ws + 4352u * 1024u);             // 256 KB
    unsigned short* ridx   = (unsigned short*)(ws + 4608u * 1024u);    // 128 KB
    int* cnt               = (int*)(ws + 4736u * 1024u);               // 128 B
    unsigned short* Ab     = (unsigned short*)(ws + 5120u * 1024u);    // 128 MB
    const size_t need = 5120ull * 1024ull + 131072ull * 1024ull;

    prep_index<<<1056, 256, 0, stream>>>(W, Um, mask, Bt, wsumrm, score, out, ridx, cnt);
    if (ws_size >= need) {
        dim3 gg(512, 32);
        gather_convert<<<gg, 256, 0, stream>>>(lhs, ridx, cnt, Ab);
        score_gemm_v3<<<4096, 256, 0, stream>>>(Ab, Bt, v, cnt, score);
        softmax_wsum<<<512, 256, 0, stream>>>(score, cnt, Ab, out);
    } else {
        dim3 g1(8, 512);
        score_gemm_f32stage<<<g1, 256, 0, stream>>>(lhs, wsumrm, v, score);
        softmax_kernel<<<32, 256, 0, stream>>>(score, mask, alphac);
        wsum_kernel<<<2048, 256, 0, stream>>>(lhs, alphac, out);
    }
}